// Round 2
// baseline (363.011 us; speedup 1.0000x reference)
//
#include <hip/hip_runtime.h>
#include <stdint.h>

// Problem constants (fixed for this instance)
#define IN_C   128
#define HID_C  128
#define NREL   8
#define K_TOTAL (NREL * IN_C)   // 1024
#define KHALF   512             // relations 0-3 / 4-7 per pass
#define TILE_M  16              // nodes per block
#define SROW    520             // 512 + 8 pad floats (bank rotation, keeps 16B align)

typedef float  f32x4  __attribute__((ext_vector_type(4)));
typedef __bf16 bf16x8 __attribute__((ext_vector_type(8)));
typedef short  s16x8  __attribute__((ext_vector_type(8)));

__device__ __forceinline__ unsigned short f2bf(float f) {
    unsigned int u = __float_as_uint(f);
    u += 0x7fffu + ((u >> 16) & 1u);   // round-to-nearest-even
    return (unsigned short)(u >> 16);
}

__global__ void zero_count_kernel(unsigned int* count) { *count = 0u; }

// ---------------- prep: compute-node list + W -> bf16 transposed [c][r*128+k]
__global__ __launch_bounds__(256) void prep_kernel(
        const float* __restrict__ W, const int* __restrict__ hmap,
        unsigned short* __restrict__ Wt, int* __restrict__ list,
        unsigned int* __restrict__ count, int NN, int WE) {
    int tid = blockIdx.x * blockDim.x + threadIdx.x;
    if (tid < NN) {
        if (hmap[tid] == -1) {
            unsigned int p = atomicAdd(count, 1u);
            list[p] = tid;
        }
    }
    if (tid < WE) {
        int r   = tid >> 14;      // / (128*128)
        int rem = tid & 16383;
        int k   = rem >> 7;       // / 128
        int c   = rem & 127;
        Wt[(size_t)c * K_TOTAL + r * IN_C + k] = f2bf(W[tid]);
    }
}

// ---------------- history nodes: copy buffer row to both output halves
__global__ __launch_bounds__(256) void history_kernel(
        const int* __restrict__ hmap, const float* __restrict__ hbuf,
        float* __restrict__ out, int NN) {
    int gid = blockIdx.x * blockDim.x + threadIdx.x;
    int n = gid >> 5;           // node
    int q = gid & 31;           // float4 index within row (128 floats = 32 f32x4)
    if (n >= NN) return;
    if (hmap[n] != -1) {
        const f32x4* src = (const f32x4*)hbuf;
        f32x4 v = src[(size_t)n * 32 + q];
        f32x4* o = (f32x4*)out;
        o[(size_t)n * 32 + q] = v;
        o[(size_t)NN * 32 + (size_t)n * 32 + q] = v;
    }
}

// ---------------- fused gather-sum + bf16 MFMA GEMM + epilogue
__global__ __launch_bounds__(256) void gemm_kernel(
        const float* __restrict__ x,
        const int* __restrict__ ptr,
        const int* __restrict__ idx,
        const int* __restrict__ ety,
        const unsigned short* __restrict__ Wt,
        const int* __restrict__ list,
        const unsigned int* __restrict__ count,
        float* __restrict__ out, int NN) {
    __shared__ float S[TILE_M * SROW];     // 16*520*4 = 33280 B
    __shared__ int   nids[TILE_M];
    __shared__ float invdeg[TILE_M];

    unsigned int cnt = *count;
    int rowbase = blockIdx.x * TILE_M;
    if (rowbase >= (int)cnt) return;       // uniform exit, before any barrier

    int t = threadIdx.x;
    if (t < TILE_M) {
        int row = rowbase + t;
        int nid = -1; float idg = 0.f;
        if (row < (int)cnt) {
            nid = list[row];
            int d = ptr[nid + 1] - ptr[nid];
            idg = 1.0f / (float)d;
        }
        nids[t] = nid;
        invdeg[t] = idg;
    }

    f32x4 acc0 = {0.f, 0.f, 0.f, 0.f};
    f32x4 acc1 = {0.f, 0.f, 0.f, 0.f};
    int wave   = t >> 6;
    int lane   = t & 63;
    int chbase = wave * 32;                // each wave owns 32 output channels
    int quad   = lane >> 4;
    int l16    = lane & 15;

    int gn = t >> 4;                       // gather: node 0..15
    int gc = (t & 15) * 8;                 // gather: 8-float channel chunk

    for (int pass = 0; pass < 2; ++pass) {
        __syncthreads();                   // meta visible / prior-pass S reads done
        // zero S
        for (int i = t; i < TILE_M * SROW / 4; i += 256)
            ((f32x4*)S)[i] = f32x4{0.f, 0.f, 0.f, 0.f};
        __syncthreads();
        // gather-accumulate this relation half
        int nid = nids[gn];
        if (nid >= 0) {
            int e0 = ptr[nid];
            int e1 = ptr[nid + 1];
            for (int e = e0; e < e1; ++e) {
                int r = ety[e];
                if ((r >> 2) != pass) continue;
                int src = idx[e];
                const float* xp = x + (size_t)src * IN_C + gc;
                float* sp = S + gn * SROW + (r & 3) * IN_C + gc;
                f32x4 a0 = *(const f32x4*)(xp);
                f32x4 a1 = *(const f32x4*)(xp + 4);
                *(f32x4*)(sp)     += a0;
                *(f32x4*)(sp + 4) += a1;
            }
        }
        __syncthreads();
        // MFMA over this K half
        const float* arow = S + l16 * SROW + quad * 8;
        const unsigned short* bbase =
            Wt + (size_t)(chbase + l16) * K_TOTAL + pass * KHALF + quad * 8;
        for (int ks = 0; ks < KHALF; ks += 32) {
            const float* ap = arow + ks;
            f32x4 lo = *(const f32x4*)ap;
            f32x4 hi = *(const f32x4*)(ap + 4);
            s16x8 a;
            a[0] = (short)f2bf(lo[0]); a[1] = (short)f2bf(lo[1]);
            a[2] = (short)f2bf(lo[2]); a[3] = (short)f2bf(lo[3]);
            a[4] = (short)f2bf(hi[0]); a[5] = (short)f2bf(hi[1]);
            a[6] = (short)f2bf(hi[2]); a[7] = (short)f2bf(hi[3]);
            s16x8 b0 = *(const s16x8*)(bbase + ks);
            s16x8 b1 = *(const s16x8*)(bbase + ks + 16 * K_TOTAL);
            union { s16x8 s; bf16x8 b; } ua, ub0, ub1;
            ua.s = a; ub0.s = b0; ub1.s = b1;
            acc0 = __builtin_amdgcn_mfma_f32_16x16x32_bf16(ua.b, ub0.b, acc0, 0, 0, 0);
            acc1 = __builtin_amdgcn_mfma_f32_16x16x32_bf16(ua.b, ub1.b, acc1, 0, 0, 0);
        }
    }

    // epilogue: C/D layout col=lane&15, row=(lane>>4)*4+reg
    size_t half = (size_t)NN * HID_C;
    #pragma unroll
    for (int v = 0; v < 4; ++v) {
        int rowl = quad * 4 + v;
        int nid = nids[rowl];
        if (nid < 0) continue;
        float s = invdeg[rowl];
        float v0 = acc0[v] * s;
        float v1 = acc1[v] * s;
        size_t o0 = (size_t)nid * HID_C + chbase + l16;
        out[o0]           = v0;
        out[o0 + 16]      = v1;
        out[o0 + half]        = v0;
        out[o0 + 16 + half]   = v1;
    }
}

extern "C" void kernel_launch(void* const* d_in, const int* in_sizes, int n_in,
                              void* d_out, int out_size, void* d_ws, size_t ws_size,
                              hipStream_t stream) {
    const float* x    = (const float*)d_in[0];
    const float* W    = (const float*)d_in[1];
    const int*   ptr  = (const int*)d_in[2];
    const int*   idx  = (const int*)d_in[3];
    const int*   ety  = (const int*)d_in[4];
    const int*   hmap = (const int*)d_in[5];
    const float* hbuf = (const float*)d_in[6];
    int NN = in_sizes[5];          // 100000
    int WE = in_sizes[1];          // 8*128*128
    float* out = (float*)d_out;

    // workspace layout
    unsigned int* count = (unsigned int*)d_ws;                 // 4 B
    int* list = (int*)((char*)d_ws + 256);                     // NN ints
    size_t wt_off = 256 + (((size_t)NN * 4 + 4095) / 4096) * 4096;
    unsigned short* Wt = (unsigned short*)((char*)d_ws + wt_off);  // 256 KB

    zero_count_kernel<<<1, 1, 0, stream>>>(count);

    int total = WE > NN ? WE : NN;
    prep_kernel<<<(total + 255) / 256, 256, 0, stream>>>(W, hmap, Wt, list, count, NN, WE);
    history_kernel<<<((size_t)NN * 32 + 255) / 256, 256, 0, stream>>>(hmap, hbuf, out, NN);
    gemm_kernel<<<(NN + TILE_M - 1) / TILE_M, 256, 0, stream>>>(
        x, ptr, idx, ety, Wt, list, count, out, NN);
}

// Round 3
// 309.972 us; speedup vs baseline: 1.1711x; 1.1711x over previous
//
#include <hip/hip_runtime.h>
#include <stdint.h>

// Problem constants (fixed for this instance)
#define IN_C   128
#define HID_C  128
#define NREL   8
#define K_TOTAL (NREL * IN_C)   // 1024
#define TILE_M  16              // nodes per block
#define SRB     1032            // bf16 units per node row in LDS (1024 + 8 pad; 1032 % 64 == 8
                                //  -> both LDS write and read phases spread across all bank quads)

typedef float  f32x4  __attribute__((ext_vector_type(4)));
typedef __bf16 bf16x8 __attribute__((ext_vector_type(8)));
typedef short  s16x8  __attribute__((ext_vector_type(8)));
typedef unsigned short u16;

__device__ __forceinline__ unsigned short f2bf(float f) {
    unsigned int u = __float_as_uint(f);
    u += 0x7fffu + ((u >> 16) & 1u);   // round-to-nearest-even
    return (unsigned short)(u >> 16);
}

__global__ void zero_count_kernel(unsigned int* count) { *count = 0u; }

// ---------------- prep: compute-node list (wave-aggregated atomics) + W -> bf16 [c][r*128+k]
__global__ __launch_bounds__(256) void prep_kernel(
        const float* __restrict__ W, const int* __restrict__ hmap,
        unsigned short* __restrict__ Wt, int* __restrict__ list,
        unsigned int* __restrict__ count, int NN, int WE) {
    int tid = blockIdx.x * blockDim.x + threadIdx.x;

    bool active = (tid < NN) && (hmap[tid] == -1);
    unsigned long long mask = __ballot(active);
    if (mask) {
        int lane   = threadIdx.x & 63;
        int leader = __ffsll((unsigned long long)mask) - 1;
        unsigned base = 0;
        if (lane == leader) base = atomicAdd(count, (unsigned)__popcll(mask));
        base = __shfl(base, leader, 64);
        if (active) {
            int off = __popcll(mask & ((1ull << lane) - 1ull));
            list[base + off] = tid;
        }
    }

    if (tid < WE) {
        int r   = tid >> 14;      // / (128*128)
        int rem = tid & 16383;
        int k   = rem >> 7;       // / 128
        int c   = rem & 127;
        Wt[(size_t)c * K_TOTAL + r * IN_C + k] = f2bf(W[tid]);
    }
}

// ---------------- history nodes: copy buffer row to both output halves
__global__ __launch_bounds__(256) void history_kernel(
        const int* __restrict__ hmap, const float* __restrict__ hbuf,
        float* __restrict__ out, int NN) {
    int gid = blockIdx.x * blockDim.x + threadIdx.x;
    int n = gid >> 5;           // node
    int q = gid & 31;           // float4 index within row
    if (n >= NN) return;
    if (hmap[n] != -1) {
        const f32x4* src = (const f32x4*)hbuf;
        f32x4 v = src[(size_t)n * 32 + q];
        f32x4* o = (f32x4*)out;
        o[(size_t)n * 32 + q] = v;
        o[(size_t)NN * 32 + (size_t)n * 32 + q] = v;
    }
}

// ---------------- fused gather (register one-hot accumulate) + bf16 MFMA GEMM
__global__ __launch_bounds__(256) void gemm_kernel(
        const float* __restrict__ x,
        const int* __restrict__ ptr,
        const int* __restrict__ idx,
        const int* __restrict__ ety,
        const unsigned short* __restrict__ Wt,
        const int* __restrict__ list,
        const unsigned int* __restrict__ count,
        float* __restrict__ out, int NN) {
    __shared__ u16      S[TILE_M * SRB];      // 33024 B, bf16 staged A-tile
    __shared__ unsigned meta[TILE_M * 16];    // packed src | rel<<27, one 16-edge chunk
    __shared__ int      nids[TILE_M];
    __shared__ int      degs[TILE_M];
    __shared__ float    invdeg[TILE_M];

    unsigned int cnt = *count;
    int rowbase = blockIdx.x * TILE_M;
    if (rowbase >= (int)cnt) return;          // uniform exit, before any barrier

    int t = threadIdx.x;
    if (t < TILE_M) {
        int row = rowbase + t;
        int nid = -1, d = 0; float idg = 0.f;
        if (row < (int)cnt) {
            nid = list[row];
            int e0 = ptr[nid], e1 = ptr[nid + 1];
            d = e1 - e0;
            idg = (d > 0) ? 1.0f / (float)d : 0.f;
        }
        nids[t] = nid; degs[t] = d; invdeg[t] = idg;
    }
    __syncthreads();

    int n = t >> 4;            // node slot 0..15
    int c = t & 15;            // 8-float channel chunk 0..15
    int nid = nids[n];
    int deg = degs[n];
    int e0  = (nid >= 0) ? ptr[nid] : 0;

    int maxdeg = 0;
    #pragma unroll
    for (int i = 0; i < TILE_M; ++i) maxdeg = max(maxdeg, degs[i]);

    // per-thread accumulator: 8 relations x 8 channels (64 VGPRs)
    f32x4 alo[NREL], ahi[NREL];
    #pragma unroll
    for (int r = 0; r < NREL; ++r) { alo[r] = f32x4{0,0,0,0}; ahi[r] = f32x4{0,0,0,0}; }

    for (int jb = 0; jb < maxdeg; jb += 16) {
        // stage this 16-edge chunk's meta, coalesced: thread (n,c) loads edge jb+c of node n
        {
            int j = jb + c;
            unsigned m = 0xFFFFFFFFu;
            if (nid >= 0 && j < deg) {
                int e = e0 + j;
                m = ((unsigned)idx[e]) | (((unsigned)ety[e]) << 27);
            }
            meta[t] = m;
        }
        __syncthreads();
        #pragma unroll 4
        for (int j = 0; j < 16; ++j) {
            unsigned m = meta[(n << 4) + j];
            if (m == 0xFFFFFFFFu) continue;               // never taken when deg==16
            int src = (int)(m & 0x07FFFFFFu);
            int r   = (int)(m >> 27);
            const f32x4* xp = (const f32x4*)(x + (size_t)src * IN_C + c * 8);
            f32x4 a0 = xp[0];
            f32x4 a1 = xp[1];
            #pragma unroll
            for (int rr = 0; rr < NREL; ++rr) {           // branchless one-hot accumulate
                float mk = (r == rr) ? 1.0f : 0.0f;
                alo[rr] += a0 * mk;
                ahi[rr] += a1 * mk;
            }
        }
        __syncthreads();   // meta reuse fence for next chunk
    }

    // convert once to bf16, write S tile (write-once, no zeroing needed)
    {
        u16* srow = S + n * SRB + c * 8;
        #pragma unroll
        for (int rr = 0; rr < NREL; ++rr) {
            s16x8 pk;
            pk[0] = (short)f2bf(alo[rr][0]); pk[1] = (short)f2bf(alo[rr][1]);
            pk[2] = (short)f2bf(alo[rr][2]); pk[3] = (short)f2bf(alo[rr][3]);
            pk[4] = (short)f2bf(ahi[rr][0]); pk[5] = (short)f2bf(ahi[rr][1]);
            pk[6] = (short)f2bf(ahi[rr][2]); pk[7] = (short)f2bf(ahi[rr][3]);
            *(s16x8*)(srow + rr * IN_C) = pk;
        }
    }
    __syncthreads();

    // MFMA over K=1024
    int wave = t >> 6, lane = t & 63;
    int quad = lane >> 4, l16 = lane & 15;
    int chbase = wave * 32;                 // each wave owns 32 output channels
    const u16* arow  = S + l16 * SRB + quad * 8;
    const u16* bbase = Wt + (size_t)(chbase + l16) * K_TOTAL + quad * 8;

    f32x4 acc0 = {0.f,0.f,0.f,0.f};
    f32x4 acc1 = {0.f,0.f,0.f,0.f};
    #pragma unroll 4
    for (int ks = 0; ks < K_TOTAL; ks += 32) {
        s16x8 a  = *(const s16x8*)(arow + ks);
        s16x8 b0 = *(const s16x8*)(bbase + ks);
        s16x8 b1 = *(const s16x8*)(bbase + ks + 16 * K_TOTAL);
        union { s16x8 s; bf16x8 b; } ua, ub0, ub1;
        ua.s = a; ub0.s = b0; ub1.s = b1;
        acc0 = __builtin_amdgcn_mfma_f32_16x16x32_bf16(ua.b, ub0.b, acc0, 0, 0, 0);
        acc1 = __builtin_amdgcn_mfma_f32_16x16x32_bf16(ua.b, ub1.b, acc1, 0, 0, 0);
    }

    // epilogue: C/D layout col=lane&15, row=(lane>>4)*4+reg  (verified in round 2)
    size_t half = (size_t)NN * HID_C;
    #pragma unroll
    for (int v = 0; v < 4; ++v) {
        int rowl = quad * 4 + v;
        int onid = nids[rowl];
        if (onid < 0) continue;
        float s = invdeg[rowl];
        float v0 = acc0[v] * s;
        float v1 = acc1[v] * s;
        size_t o0 = (size_t)onid * HID_C + chbase + l16;
        out[o0]             = v0;
        out[o0 + 16]        = v1;
        out[o0 + half]      = v0;
        out[o0 + 16 + half] = v1;
    }
}

extern "C" void kernel_launch(void* const* d_in, const int* in_sizes, int n_in,
                              void* d_out, int out_size, void* d_ws, size_t ws_size,
                              hipStream_t stream) {
    const float* x    = (const float*)d_in[0];
    const float* W    = (const float*)d_in[1];
    const int*   ptr  = (const int*)d_in[2];
    const int*   idx  = (const int*)d_in[3];
    const int*   ety  = (const int*)d_in[4];
    const int*   hmap = (const int*)d_in[5];
    const float* hbuf = (const float*)d_in[6];
    int NN = in_sizes[5];          // 100000
    int WE = in_sizes[1];          // 8*128*128
    float* out = (float*)d_out;

    // workspace layout
    unsigned int* count = (unsigned int*)d_ws;                 // 4 B
    int* list = (int*)((char*)d_ws + 256);                     // NN ints
    size_t wt_off = 256 + (((size_t)NN * 4 + 4095) / 4096) * 4096;
    unsigned short* Wt = (unsigned short*)((char*)d_ws + wt_off);  // 256 KB

    zero_count_kernel<<<1, 1, 0, stream>>>(count);

    int total = WE > NN ? WE : NN;
    prep_kernel<<<(total + 255) / 256, 256, 0, stream>>>(W, hmap, Wt, list, count, NN, WE);
    history_kernel<<<((size_t)NN * 32 + 255) / 256, 256, 0, stream>>>(hmap, hbuf, out, NN);
    gemm_kernel<<<(NN + TILE_M - 1) / TILE_M, 256, 0, stream>>>(
        x, ptr, idx, ety, Wt, list, count, out, NN);
}

// Round 4
// 300.179 us; speedup vs baseline: 1.2093x; 1.0326x over previous
//
#include <hip/hip_runtime.h>
#include <stdint.h>

// Problem constants (fixed for this instance)
#define IN_C   128
#define HID_C  128
#define NREL   8
#define K_TOTAL (NREL * IN_C)   // 1024
#define TILE_M  16              // nodes per block
#define SRB     1032            // bf16 units per node row in LDS (1024 + 8 pad)

typedef float  f32x4  __attribute__((ext_vector_type(4)));
typedef __bf16 bf16x8 __attribute__((ext_vector_type(8)));
typedef short  s16x8  __attribute__((ext_vector_type(8)));
typedef unsigned short u16;

__device__ __forceinline__ unsigned short f2bf(float f) {
    unsigned int u = __float_as_uint(f);
    u += 0x7fffu + ((u >> 16) & 1u);   // round-to-nearest-even
    return (unsigned short)(u >> 16);
}

__global__ void zero_count_kernel(unsigned int* count) { *count = 0u; }

// ---------------- prep: compute-node list (wave-aggregated atomics) + W -> bf16 [c][r*128+k]
__global__ __launch_bounds__(256) void prep_kernel(
        const float* __restrict__ W, const int* __restrict__ hmap,
        unsigned short* __restrict__ Wt, int* __restrict__ list,
        unsigned int* __restrict__ count, int NN, int WE) {
    int tid = blockIdx.x * blockDim.x + threadIdx.x;

    bool active = (tid < NN) && (hmap[tid] == -1);
    unsigned long long mask = __ballot(active);
    if (mask) {
        int lane   = threadIdx.x & 63;
        int leader = __ffsll((unsigned long long)mask) - 1;
        unsigned base = 0;
        if (lane == leader) base = atomicAdd(count, (unsigned)__popcll(mask));
        base = __shfl(base, leader, 64);
        if (active) {
            int off = __popcll(mask & ((1ull << lane) - 1ull));
            list[base + off] = tid;
        }
    }

    if (tid < WE) {
        int r   = tid >> 14;      // / (128*128)
        int rem = tid & 16383;
        int k   = rem >> 7;       // / 128
        int c   = rem & 127;
        Wt[(size_t)c * K_TOTAL + r * IN_C + k] = f2bf(W[tid]);
    }
}

// ---------------- history nodes: copy buffer row to both output halves
__global__ __launch_bounds__(256) void history_kernel(
        const int* __restrict__ hmap, const float* __restrict__ hbuf,
        float* __restrict__ out, int NN) {
    int gid = blockIdx.x * blockDim.x + threadIdx.x;
    int n = gid >> 5;           // node
    int q = gid & 31;           // float4 index within row
    if (n >= NN) return;
    if (hmap[n] != -1) {
        const f32x4* src = (const f32x4*)hbuf;
        f32x4 v = src[(size_t)n * 32 + q];
        f32x4* o = (f32x4*)out;
        o[(size_t)n * 32 + q] = v;
        o[(size_t)NN * 32 + (size_t)n * 32 + q] = v;
    }
}

// ---------------- fused gather (pipelined, branch-free) + bf16 MFMA GEMM
__global__ __launch_bounds__(256, 3) void gemm_kernel(
        const float* __restrict__ x,
        const int* __restrict__ ptr,
        const int* __restrict__ idx,
        const int* __restrict__ ety,
        const unsigned short* __restrict__ Wt,
        const int* __restrict__ list,
        const unsigned int* __restrict__ count,
        float* __restrict__ out, int NN) {
    __shared__ u16      S[TILE_M * SRB];      // 33024 B, bf16 staged A-tile
    __shared__ unsigned meta[TILE_M * 16];    // packed src | rel<<27
    __shared__ int      nids[TILE_M];
    __shared__ int      degs[TILE_M];
    __shared__ float    invdeg[TILE_M];

    unsigned int cnt = *count;
    int rowbase = blockIdx.x * TILE_M;
    if (rowbase >= (int)cnt) return;          // uniform exit, before any barrier

    int t = threadIdx.x;
    if (t < TILE_M) {
        int row = rowbase + t;
        int nid = -1, d = 0; float idg = 0.f;
        if (row < (int)cnt) {
            nid = list[row];
            int e0 = ptr[nid], e1 = ptr[nid + 1];
            d = e1 - e0;
            idg = (d > 0) ? 1.0f / (float)d : 0.f;
        }
        nids[t] = nid; degs[t] = d; invdeg[t] = idg;
    }
    __syncthreads();

    int n = t >> 4;            // node slot 0..15
    int c = t & 15;            // 8-float channel chunk 0..15
    int nid = nids[n];
    int deg = degs[n];
    int e0  = (nid >= 0) ? ptr[nid] : 0;

    int maxdeg = 0;
    #pragma unroll
    for (int i = 0; i < TILE_M; ++i) maxdeg = max(maxdeg, degs[i]);

    // per-thread accumulator: 8 relations x 8 channels (64 VGPRs)
    f32x4 alo[NREL], ahi[NREL];
    #pragma unroll
    for (int r = 0; r < NREL; ++r) { alo[r] = f32x4{0,0,0,0}; ahi[r] = f32x4{0,0,0,0}; }

    const float* xc = x + c * 8;   // channel-chunk base

    for (int jb = 0; jb < maxdeg; jb += 16) {
        // stage this 16-edge chunk's meta, coalesced
        {
            int j = jb + c;
            unsigned m = 0xFFFFFFFFu;
            if (nid >= 0 && j < deg) {
                int e = e0 + j;
                m = ((unsigned)idx[e]) | (((unsigned)ety[e]) << 27);
            }
            meta[t] = m;
        }
        __syncthreads();

        // pull all 16 metas into registers (4 x ds_read_b128), decode branch-free
        unsigned mm[16];
        {
            uint4 q0 = *(const uint4*)(meta + (n << 4) + 0);
            uint4 q1 = *(const uint4*)(meta + (n << 4) + 4);
            uint4 q2 = *(const uint4*)(meta + (n << 4) + 8);
            uint4 q3 = *(const uint4*)(meta + (n << 4) + 12);
            mm[0]=q0.x;  mm[1]=q0.y;  mm[2]=q0.z;  mm[3]=q0.w;
            mm[4]=q1.x;  mm[5]=q1.y;  mm[6]=q1.z;  mm[7]=q1.w;
            mm[8]=q2.x;  mm[9]=q2.y;  mm[10]=q2.z; mm[11]=q2.w;
            mm[12]=q3.x; mm[13]=q3.y; mm[14]=q3.z; mm[15]=q3.w;
        }
        int offs[16];   // element offset of this thread's chunk in x
        int rel[16];    // relation id, 31 = inactive (one-hot never matches)
        #pragma unroll
        for (int j = 0; j < 16; ++j) {
            unsigned m = mm[j];
            bool valid = (m != 0xFFFFFFFFu);
            int src = valid ? (int)(m & 0x07FFFFFFu) : 0;
            rel[j]  = valid ? (int)(m >> 27) : 31;
            offs[j] = src * IN_C;
        }

        // software pipeline: 4-edge batches, double-buffered (8 edges in flight)
        f32x4 blo[4], bhi[4];
        #pragma unroll
        for (int u = 0; u < 4; ++u) {
            const f32x4* p = (const f32x4*)(xc + offs[u]);
            blo[u] = p[0]; bhi[u] = p[1];
        }
        #pragma unroll
        for (int b = 0; b < 4; ++b) {
            f32x4 nlo[4], nhi[4];
            if (b < 3) {
                #pragma unroll
                for (int u = 0; u < 4; ++u) {
                    const f32x4* p = (const f32x4*)(xc + offs[(b + 1) * 4 + u]);
                    nlo[u] = p[0]; nhi[u] = p[1];
                }
            }
            #pragma unroll
            for (int u = 0; u < 4; ++u) {
                int r = rel[b * 4 + u];
                #pragma unroll
                for (int rr = 0; rr < NREL; ++rr) {       // branchless one-hot
                    float mk = (r == rr) ? 1.0f : 0.0f;
                    alo[rr] += blo[u] * mk;
                    ahi[rr] += bhi[u] * mk;
                }
            }
            if (b < 3) {
                #pragma unroll
                for (int u = 0; u < 4; ++u) { blo[u] = nlo[u]; bhi[u] = nhi[u]; }
            }
        }
        __syncthreads();   // meta reuse fence for next chunk
    }

    // convert once to bf16, write S tile (write-once, no zeroing needed)
    {
        u16* srow = S + n * SRB + c * 8;
        #pragma unroll
        for (int rr = 0; rr < NREL; ++rr) {
            s16x8 pk;
            pk[0] = (short)f2bf(alo[rr][0]); pk[1] = (short)f2bf(alo[rr][1]);
            pk[2] = (short)f2bf(alo[rr][2]); pk[3] = (short)f2bf(alo[rr][3]);
            pk[4] = (short)f2bf(ahi[rr][0]); pk[5] = (short)f2bf(ahi[rr][1]);
            pk[6] = (short)f2bf(ahi[rr][2]); pk[7] = (short)f2bf(ahi[rr][3]);
            *(s16x8*)(srow + rr * IN_C) = pk;
        }
    }
    __syncthreads();

    // MFMA over K=1024
    int wave = t >> 6, lane = t & 63;
    int quad = lane >> 4, l16 = lane & 15;
    int chbase = wave * 32;                 // each wave owns 32 output channels
    const u16* arow  = S + l16 * SRB + quad * 8;
    const u16* bbase = Wt + (size_t)(chbase + l16) * K_TOTAL + quad * 8;

    f32x4 acc0 = {0.f,0.f,0.f,0.f};
    f32x4 acc1 = {0.f,0.f,0.f,0.f};
    #pragma unroll 8
    for (int ks = 0; ks < K_TOTAL; ks += 32) {
        s16x8 a  = *(const s16x8*)(arow + ks);
        s16x8 b0 = *(const s16x8*)(bbase + ks);
        s16x8 b1 = *(const s16x8*)(bbase + ks + 16 * K_TOTAL);
        union { s16x8 s; bf16x8 b; } ua, ub0, ub1;
        ua.s = a; ub0.s = b0; ub1.s = b1;
        acc0 = __builtin_amdgcn_mfma_f32_16x16x32_bf16(ua.b, ub0.b, acc0, 0, 0, 0);
        acc1 = __builtin_amdgcn_mfma_f32_16x16x32_bf16(ua.b, ub1.b, acc1, 0, 0, 0);
    }

    // epilogue: C/D layout col=lane&15, row=(lane>>4)*4+reg  (verified round 2)
    size_t half = (size_t)NN * HID_C;
    #pragma unroll
    for (int v = 0; v < 4; ++v) {
        int rowl = quad * 4 + v;
        int onid = nids[rowl];
        if (onid < 0) continue;
        float s = invdeg[rowl];
        float v0 = acc0[v] * s;
        float v1 = acc1[v] * s;
        size_t o0 = (size_t)onid * HID_C + chbase + l16;
        out[o0]             = v0;
        out[o0 + 16]        = v1;
        out[o0 + half]      = v0;
        out[o0 + 16 + half] = v1;
    }
}

extern "C" void kernel_launch(void* const* d_in, const int* in_sizes, int n_in,
                              void* d_out, int out_size, void* d_ws, size_t ws_size,
                              hipStream_t stream) {
    const float* x    = (const float*)d_in[0];
    const float* W    = (const float*)d_in[1];
    const int*   ptr  = (const int*)d_in[2];
    const int*   idx  = (const int*)d_in[3];
    const int*   ety  = (const int*)d_in[4];
    const int*   hmap = (const int*)d_in[5];
    const float* hbuf = (const float*)d_in[6];
    int NN = in_sizes[5];          // 100000
    int WE = in_sizes[1];          // 8*128*128
    float* out = (float*)d_out;

    // workspace layout
    unsigned int* count = (unsigned int*)d_ws;                 // 4 B
    int* list = (int*)((char*)d_ws + 256);                     // NN ints
    size_t wt_off = 256 + (((size_t)NN * 4 + 4095) / 4096) * 4096;
    unsigned short* Wt = (unsigned short*)((char*)d_ws + wt_off);  // 256 KB

    zero_count_kernel<<<1, 1, 0, stream>>>(count);

    int total = WE > NN ? WE : NN;
    prep_kernel<<<(total + 255) / 256, 256, 0, stream>>>(W, hmap, Wt, list, count, NN, WE);
    history_kernel<<<((size_t)NN * 32 + 255) / 256, 256, 0, stream>>>(hmap, hbuf, out, NN);
    gemm_kernel<<<(NN + TILE_M - 1) / TILE_M, 256, 0, stream>>>(
        x, ptr, idx, ety, Wt, list, count, out, NN);
}